// Round 14
// baseline (17369.765 us; speedup 1.0000x reference)
//
#include <hip/hip_runtime.h>
#include <hip/hip_fp16.h>

#define BB 64
#define SS 512
#define DD 1024
#define HH 1024
#define NBLK 256
#define HMASK 63   // h0t MALL ring depth 64
#define LMASK 3    // local h ring depth 4
#define GMASK 7    // gi ring depth 8

typedef _Float16 f16;
typedef unsigned long long u64;
typedef __attribute__((ext_vector_type(8))) _Float16 f16x8;
typedef __attribute__((ext_vector_type(4))) _Float16 f16x4;
typedef __attribute__((ext_vector_type(4))) float f32x4;

struct GruWS {
  unsigned sigT[4 * 32 * 16];   // MALL signals: (role*32+member)*16, 64B lines, value = completed s+1
  unsigned sigL[2 * 32 * 16];   // XCD-local signals: role1 (r13=0) / role3 (r13=1)
  f16 gi0[8][3 * HH][BB];       // [slot s&7][3H][B]   MALL path
  f16 gi1[8][3 * HH][BB];
  f16 h0t[64][BB][HH];          // [slot s&63][B][H]   MALL copy of h0 (for L1gi), swap-stores
  f16 h0loc[4][BB][HH];         // [slot s&3][B][H]    XCD1-local (L0gh peers)
  f16 h1loc[4][BB][HH];         // XCD3-local (L1gh peers)
};

// ---- primitives ----
__device__ __forceinline__ f16x8 ld_dev_16B(const void* p) {   // L1-bypass, L2-cached
  f16x8 r;
  asm volatile("global_load_dwordx4 %0, %1, off sc0" : "=v"(r) : "v"(p) : "memory");
  return r;
}
__device__ __forceinline__ void st_loc_16B(void* p, f16x8 v) { // L2 writeback (XCD-local)
  asm volatile("global_store_dwordx4 %0, %1, off sc0" :: "v"(p), "v"(v) : "memory");
}
__device__ __forceinline__ void st_sys_16B(void* p, f16x8 v) { // bypass, MALL/HBM
  asm volatile("global_store_dwordx4 %0, %1, off sc0 sc1" :: "v"(p), "v"(v) : "memory");
}
__device__ __forceinline__ void st_mall_16B(void* p, f16x8 v) { // atomic swaps: execute AT MALL, line stays hot
  union { f16x8 v; u64 q[2]; } u; u.v = v;
  asm volatile("global_atomic_swap_x2 %0, %1, off sc1" :: "v"((u64*)p), "v"(u.q[0]) : "memory");
  asm volatile("global_atomic_swap_x2 %0, %1, off sc1" :: "v"((u64*)p + 1), "v"(u.q[1]) : "memory");
}
__device__ __forceinline__ void sig_swap(unsigned* p, unsigned v) {   // MALL-scope signal
  asm volatile("global_atomic_swap %0, %1, off sc1" :: "v"(p), "v"(v) : "memory");
}
__device__ __forceinline__ void sigl_swap(unsigned* p, unsigned v) {  // L2-scope signal
  asm volatile("global_atomic_swap %0, %1, off" :: "v"(p), "v"(v) : "memory");
}
__device__ __forceinline__ void drain_vm() {
  asm volatile("s_waitcnt vmcnt(0)" ::: "memory");
  __builtin_amdgcn_sched_barrier(0);
}
__device__ __forceinline__ f16x4 ld_sys_f16x4(const f16* p) {
  u64 q = __hip_atomic_load((const u64*)p, __ATOMIC_RELAXED, __HIP_MEMORY_SCOPE_SYSTEM);
  union { u64 q; f16x4 v; } u; u.q = q; return u.v;
}
__device__ __forceinline__ float ld_sys_f16s(const f16* p) {
  unsigned short s = __hip_atomic_load((const unsigned short*)p, __ATOMIC_RELAXED, __HIP_MEMORY_SCOPE_SYSTEM);
  union { unsigned short s; f16 h; } u; u.s = s; return (float)u.h;
}
__device__ __forceinline__ void nap(int it) {
  if (it < 3) __builtin_amdgcn_s_sleep(1);
  else        __builtin_amdgcn_s_sleep(16);
}

__device__ __forceinline__ void wait1(const unsigned* p, int target, int& seen) {
  if (target <= 0 || seen >= target) return;
  int it = 0;
  for (;;) {
    unsigned v;
    asm volatile("global_load_dword %0, %1, off sc0 sc1" : "=v"(v) : "v"(p));
    asm volatile("s_waitcnt vmcnt(0)" ::: "memory");
    if ((int)v >= target) { seen = (int)v; break; }
    nap(++it);
  }
  asm volatile("" ::: "memory");
}
__device__ __forceinline__ void wait32(const unsigned* rowbase, int target, int lane, int& seen) {
  if (target <= 0 || seen >= target) return;
  const unsigned* p = rowbase + (lane & 31) * 16;
  int it = 0;
  unsigned v;
  for (;;) {
    asm volatile("global_load_dword %0, %1, off sc0 sc1" : "=v"(v) : "v"(p));
    asm volatile("s_waitcnt vmcnt(0)" ::: "memory");
    if (__all((int)v >= target)) break;
    nap(++it);
  }
  int m = (int)v;
#pragma unroll
  for (int off = 1; off < 32; off <<= 1) {
    int o = __shfl_xor(m, off);
    m = (o < m) ? o : m;
  }
  seen = m;
  asm volatile("" ::: "memory");
}
// role-2: per-wave poll of its 8 h-producers' MALL lines
__device__ __forceinline__ void wait_hot8(const unsigned* sig, int hbase, int wv,
                                          int htgt, int lane, int& seenh) {
  if (htgt <= 0 || seenh >= htgt) return;
  const unsigned* p = sig + ((hbase + wv * 8 + (lane & 7)) << 4);
  int it = 0;
  unsigned v;
  for (;;) {
    asm volatile("global_load_dword %0, %1, off sc0 sc1" : "=v"(v) : "v"(p));
    asm volatile("s_waitcnt vmcnt(0)" ::: "memory");
    if (__all((int)v >= htgt)) break;
    nap(++it);
  }
  int m = (int)v;
#pragma unroll
  for (int off = 1; off < 8; off <<= 1) { int o = __shfl_xor(m, off); m = (o < m) ? o : m; }
  seenh = __shfl(m, 0);
  asm volatile("" ::: "memory");
}
// XCD-local per-wave poll of 8 peer producers (sc0 / L2); falls back to MALL sigs
// after 64 idle iterations (robust if L2-scope atomics don't behave as modeled).
__device__ __forceinline__ void wait8L(const unsigned* sigL, const unsigned* sigTrow,
                                       int r13, int wv, int target, int lane, int& seen) {
  if (target <= 0 || seen >= target) return;
  const unsigned* p = sigL + ((r13 * 32 + wv * 8 + (lane & 7)) << 4);
  int it = 0;
  unsigned v;
  for (;;) {
    asm volatile("global_load_dword %0, %1, off sc0" : "=v"(v) : "v"(p));
    asm volatile("s_waitcnt vmcnt(0)" ::: "memory");
    if (__all((int)v >= target)) break;
    if (++it > 64) {              // fallback: known-good MALL path
      int d = seen;
      wait32(sigTrow, target, lane, d);
      seen = d;
      return;
    }
    nap(it);
  }
  int m = (int)v;
#pragma unroll
  for (int off = 1; off < 8; off <<= 1) { int o = __shfl_xor(m, off); m = (o < m) ? o : m; }
  seen = __shfl(m, 0);
  asm volatile("" ::: "memory");
}

// flush every XCD's L2 (stale dirty lines from previous launch) BEFORE init writes
__global__ void gru_fence() { __threadfence(); }

__global__ void gru_init(GruWS* __restrict__ ws) {
  int i = threadIdx.x;
  if (i < 128) __hip_atomic_store(&ws->sigT[i * 16], 0u, __ATOMIC_RELAXED, __HIP_MEMORY_SCOPE_SYSTEM);
  if (i < 64)  __hip_atomic_store(&ws->sigL[i * 16], 0u, __ATOMIC_RELAXED, __HIP_MEMORY_SCOPE_SYSTEM);
}

// per-wave K-quarter MFMA + cross-wave LDS K-reduce (one syncthreads inside)
__device__ __forceinline__ void mma_pass(const f16x8 areg[8][4], const f16x8* bnt,
                                         float* red, int lane, int wave, f32x4 acc[3]) {
  f32x4 pacc[4][3];
#pragma unroll
  for (int m = 0; m < 4; ++m)
#pragma unroll
    for (int g = 0; g < 3; ++g) pacc[m][g] = (f32x4){0.f, 0.f, 0.f, 0.f};
#pragma unroll
  for (int kk = 0; kk < 8; ++kk)
#pragma unroll
    for (int m = 0; m < 4; ++m)
#pragma unroll
      for (int g = 0; g < 3; ++g)
        pacc[m][g] = __builtin_amdgcn_mfma_f32_16x16x32_f16(areg[kk][m], bnt[g * 8 + kk], pacc[m][g], 0, 0, 0);
#pragma unroll
  for (int m = 0; m < 4; ++m)
    if (m != wave)
#pragma unroll
      for (int g = 0; g < 3; ++g)
#pragma unroll
        for (int r = 0; r < 4; ++r)
          red[(((wave * 4 + m) * 3 + g) * 4 + r) * 64 + lane] = pacc[m][g][r];
  __syncthreads();
#pragma unroll
  for (int g = 0; g < 3; ++g) {
    f32x4 a = pacc[wave][g];
#pragma unroll
    for (int sw = 0; sw < 4; ++sw)
      if (sw != wave)
#pragma unroll
        for (int r = 0; r < 4; ++r)
          a[r] += red[(((sw * 4 + wave) * 3 + g) * 4 + r) * 64 + lane];
    acc[g] = a;
  }
}

__global__ __launch_bounds__(256, 1) void gru_main(
    const float* __restrict__ x, const float* __restrict__ xmask,
    const float* __restrict__ h0in,
    const float* __restrict__ Wih0, const float* __restrict__ Whh0,
    const float* __restrict__ bih0, const float* __restrict__ bhh0,
    const float* __restrict__ Wih1, const float* __restrict__ Whh1,
    const float* __restrict__ bih1, const float* __restrict__ bhh1,
    float* __restrict__ out, GruWS* __restrict__ ws) {
  const int bid = blockIdx.x;
  const int grp = bid & 7;          // XCD binding: role r on XCD r (bid%8 -> XCD, m09)
  if (grp >= 4) return;             // XCDs 4-7 idle
  __shared__ __align__(16) char ldsbuf[49152];
  float* red = (float*)ldsbuf;

  const int gidx = bid >> 3;        // member 0..31
  const int base = gidx * 32;
  const int tid = threadIdx.x;
  const int lane = tid & 63;
  const int wave = tid >> 6;
  const int l15 = lane & 15;
  const int kgrp = lane >> 4;
  const int b0 = wave * 16 + kgrp * 4;
  const int kbase0 = wave * 256 + kgrp * 8;
  unsigned* sig = ws->sigT;
  unsigned* mysig = &sig[(grp * 32 + gidx) * 16];

  const float* Wsrc = (grp == 0) ? Wih0 : (grp == 1) ? Whh0 : (grp == 2) ? Wih1 : Whh1;
  f16x8 breg[2][3][8];
#pragma unroll
  for (int nt = 0; nt < 2; ++nt)
#pragma unroll
    for (int g = 0; g < 3; ++g)
#pragma unroll
      for (int kk = 0; kk < 8; ++kk) {
        const float* p = Wsrc + (long)(g * HH + base + nt * 16 + l15) * DD + kbase0 + kk * 32;
        float4 v0 = *(const float4*)p;
        float4 v1 = *(const float4*)(p + 4);
        f16x8 t;
        t[0] = (f16)v0.x; t[1] = (f16)v0.y; t[2] = (f16)v0.z; t[3] = (f16)v0.w;
        t[4] = (f16)v1.x; t[5] = (f16)v1.y; t[6] = (f16)v1.z; t[7] = (f16)v1.w;
        breg[nt][g][kk] = t;
      }

  if (grp == 0 || grp == 2) {
    // ============ gi roles: gi = A @ Wih^T + (bih + bhh_{r,z}) ============
    const int layer = (grp == 2);
    const float* bih = layer ? bih1 : bih0;
    const float* bhh = layer ? bhh1 : bhh0;
    float bias[2][3];
#pragma unroll
    for (int nt = 0; nt < 2; ++nt)
#pragma unroll
      for (int g = 0; g < 3; ++g) {
        int colg = base + nt * 16 + l15;
        bias[nt][g] = bih[g * HH + colg] + (g < 2 ? bhh[g * HH + colg] : 0.0f);
      }
    int seen_slot = 0, seen_h = 0;

    for (int s = 0; s < SS; ++s) {
      if (!layer) {
        wait1(&sig[(1 * 32 + gidx) * 16], s - (GMASK - 1), seen_slot);   // gi0 slot free
      } else {
        wait1(&sig[(3 * 32 + gidx) * 16], s - (GMASK - 1), seen_slot);   // gi1 slot free
        wait_hot8(sig, 1 * 32, wave, s + 1, lane, seen_h);               // h0(s) at MALL
        if ((s & 31) == 0) __threadfence();                              // refresh sc0-cached h0t
      }
      {
        f16x8 areg[8][4];
        if (!layer) {
#pragma unroll
          for (int kk = 0; kk < 8; ++kk)
#pragma unroll
            for (int m = 0; m < 4; ++m) {
              const float* p = x + (long)(m * 16 + l15) * (SS * DD) + (long)s * DD + kbase0 + kk * 32;
              float4 v0 = *(const float4*)p;
              float4 v1 = *(const float4*)(p + 4);
              f16x8 a;
              a[0] = (f16)v0.x; a[1] = (f16)v0.y; a[2] = (f16)v0.z; a[3] = (f16)v0.w;
              a[4] = (f16)v1.x; a[5] = (f16)v1.y; a[6] = (f16)v1.z; a[7] = (f16)v1.w;
              areg[kk][m] = a;
            }
        } else {
          const f16* A = &ws->h0t[s & HMASK][0][0];
#pragma unroll
          for (int kk = 0; kk < 8; ++kk)
#pragma unroll
            for (int m = 0; m < 4; ++m)
              areg[kk][m] = ld_dev_16B(A + (long)(m * 16 + l15) * HH + kbase0 + kk * 32);
        }
        drain_vm();
        f32x4 accs[2][3];
        mma_pass(areg, &breg[0][0][0], red, lane, wave, accs[0]);
        __syncthreads();
        mma_pass(areg, &breg[1][0][0], red, lane, wave, accs[1]);
        __syncthreads();

        f16* gt = (f16*)ldsbuf;   // [96][64]
#pragma unroll
        for (int nt = 0; nt < 2; ++nt)
#pragma unroll
          for (int g = 0; g < 3; ++g) {
            f16x4 o;
#pragma unroll
            for (int r = 0; r < 4; ++r) o[r] = (f16)(accs[nt][g][r] + bias[nt][g]);
            *(f16x4*)(gt + (g * 32 + nt * 16 + l15) * 64 + b0) = o;
          }
        __syncthreads();
        f16* gib = layer ? &ws->gi1[s & GMASK][0][0] : &ws->gi0[s & GMASK][0][0];
#pragma unroll
        for (int rnd = 0; rnd < 3; ++rnd) {
          int idx = rnd * 256 + tid;
          int row = idx >> 3, ch = idx & 7;
          int g = row >> 5, c = row & 31;
          f16x8 v = *(const f16x8*)(gt + row * 64 + ch * 8);
          st_sys_16B(gib + (long)(g * HH + base + c) * BB + ch * 8, v);
        }
      }
      asm volatile("s_waitcnt vmcnt(0)" ::: "memory");
      __syncthreads();
      if (tid == 0) sig_swap(mysig, (unsigned)(s + 1));
    }
  } else {
    // ============ gh roles: recurrent step (XCD-local h exchange) ============
    const int layer = (grp == 3);
    const int r13 = layer ? 1 : 0;
    const float* bhh = layer ? bhh1 : bhh0;
    unsigned* sigL = ws->sigL;
    unsigned* mysigL = &sigL[(r13 * 32 + gidx) * 16];
    const unsigned* peersT = &sig[(layer ? 3 : 1) * 32 * 16];
    float bhn[2], hold[2][4], osum[2][4];
#pragma unroll
    for (int nt = 0; nt < 2; ++nt) {
      bhn[nt] = bhh[2 * HH + base + nt * 16 + l15];
#pragma unroll
      for (int r = 0; r < 4; ++r) {
        hold[nt][r] = h0in[(long)layer * BB * HH + (long)(b0 + r) * HH + base + nt * 16 + l15];
        osum[nt][r] = 0.f;
      }
    }
    int seen_gi = 0, seen_peers = 0, seen_cons = 0;

    for (int s = 0; s < SS; ++s) {
      float mv[4];
#pragma unroll
      for (int r = 0; r < 4; ++r) mv[r] = xmask[(long)(b0 + r) * SS + s];
      // gi(s) ready (MALL, producer runs ahead -> usually cached-skip)
      wait1(&sig[((layer ? 2 : 0) * 32 + gidx) * 16], s + 1, seen_gi);
      const f16* gib = layer ? &ws->gi1[s & GMASK][0][0] : &ws->gi0[s & GMASK][0][0];
      f16x4 gfr[2][3];
#pragma unroll
      for (int nt = 0; nt < 2; ++nt)
#pragma unroll
        for (int g = 0; g < 3; ++g)
          gfr[nt][g] = ld_sys_f16x4(gib + (long)(g * HH + base + nt * 16 + l15) * BB + b0);
      if (!layer && wave == 0)
        wait32(&sig[2 * 32 * 16], s - 60, lane, seen_cons);   // h0t slot reuse guard (rare)
      // peers' h(s-1): XCD-local signals
      wait8L(sigL, peersT, r13, wave, s, lane, seen_peers);

      f16x8 areg[8][4];
      if (s == 0) {
        const float* A0 = h0in + (long)layer * BB * HH;
#pragma unroll
        for (int kk = 0; kk < 8; ++kk)
#pragma unroll
          for (int m = 0; m < 4; ++m) {
            const float* p = A0 + (long)(m * 16 + l15) * HH + kbase0 + kk * 32;
            float4 v0 = *(const float4*)p;
            float4 v1 = *(const float4*)(p + 4);
            f16x8 a;
            a[0] = (f16)v0.x; a[1] = (f16)v0.y; a[2] = (f16)v0.z; a[3] = (f16)v0.w;
            a[4] = (f16)v1.x; a[5] = (f16)v1.y; a[6] = (f16)v1.z; a[7] = (f16)v1.w;
            areg[kk][m] = a;
          }
      } else {
        const f16* A = layer ? &ws->h1loc[(s - 1) & LMASK][0][0] : &ws->h0loc[(s - 1) & LMASK][0][0];
#pragma unroll
        for (int kk = 0; kk < 8; ++kk)
#pragma unroll
          for (int m = 0; m < 4; ++m)
            areg[kk][m] = ld_dev_16B(A + (long)(m * 16 + l15) * HH + kbase0 + kk * 32);
      }
      drain_vm();

      f32x4 accs[2][3];
      mma_pass(areg, &breg[0][0][0], red, lane, wave, accs[0]);
      __syncthreads();
      mma_pass(areg, &breg[1][0][0], red, lane, wave, accs[1]);
      __syncthreads();

      f16* htile = (f16*)ldsbuf;  // [64][32]
#pragma unroll
      for (int nt = 0; nt < 2; ++nt)
#pragma unroll
        for (int r = 0; r < 4; ++r) {
          float pr = accs[nt][0][r] + (float)gfr[nt][0][r];
          float pz = accs[nt][1][r] + (float)gfr[nt][1][r];
          float ph = accs[nt][2][r] + bhn[nt];
          float rr = 1.0f / (1.0f + __expf(-pr));
          float zz = 1.0f / (1.0f + __expf(-pz));
          float nn = tanhf((float)gfr[nt][2][r] + rr * ph);
          float upd = hold[nt][r] + (1.0f - zz) * (nn - hold[nt][r]);
          if (mv[r] > 0.5f) {
            hold[nt][r] = upd;
            if (layer) osum[nt][r] += upd;
          }
          htile[(b0 + r) * 32 + nt * 16 + l15] = (f16)hold[nt][r];
        }
      __syncthreads();

      const int b = tid >> 2, ch = tid & 3;
      f16x8 hv = *(const f16x8*)(htile + b * 32 + ch * 8);
      // 1) local store (XCD L2) -> peers
      f16* hloc = layer ? &ws->h1loc[s & LMASK][0][0] : &ws->h0loc[s & LMASK][0][0];
      st_loc_16B(hloc + (long)b * HH + base + ch * 8, hv);
      asm volatile("s_waitcnt vmcnt(0)" ::: "memory");
      __syncthreads();
      if (tid == 0) sigl_swap(mysigL, (unsigned)(s + 1));   // peers unblocked (L2-local)
      if (!layer) {
        // 2) MALL copy for L1gi
        st_mall_16B(&ws->h0t[s & HMASK][0][0] + (long)b * HH + base + ch * 8, hv);
      }
      if (s == SS - 1 && layer) {
#pragma unroll
        for (int nt = 0; nt < 2; ++nt)
#pragma unroll
          for (int r = 0; r < 4; ++r) {
            int colg = base + nt * 16 + l15;
            float h0f = ld_sys_f16s(&ws->h0t[(SS - 1) & HMASK][b0 + r][colg]);  // h0(511)
            out[(long)(b0 + r) * HH + colg] =
                (osum[nt][r] + hold[nt][r] + h0f) * (1.0f / 514.0f);
          }
      }
      asm volatile("s_waitcnt vmcnt(0)" ::: "memory");
      __syncthreads();
      if (tid == 0) sig_swap(mysig, (unsigned)(s + 1));     // MALL signal (cross-role)
    }
  }
}

extern "C" void kernel_launch(void* const* d_in, const int* in_sizes, int n_in,
                              void* d_out, int out_size, void* d_ws, size_t ws_size,
                              hipStream_t stream) {
  const float* x = (const float*)d_in[0];
  const float* xmask = (const float*)d_in[1];
  const float* h0 = (const float*)d_in[2];
  const float* Wih0 = (const float*)d_in[3];
  const float* Whh0 = (const float*)d_in[4];
  const float* bih0 = (const float*)d_in[5];
  const float* bhh0 = (const float*)d_in[6];
  const float* Wih1 = (const float*)d_in[7];
  const float* Whh1 = (const float*)d_in[8];
  const float* bih1 = (const float*)d_in[9];
  const float* bhh1 = (const float*)d_in[10];
  float* out = (float*)d_out;
  GruWS* ws = (GruWS*)d_ws;

  hipLaunchKernelGGL(gru_fence, dim3(64), dim3(64), 0, stream);       // flush all XCD L2s first
  hipLaunchKernelGGL(gru_init, dim3(1), dim3(256), 0, stream, ws);    // then zero signals
  hipLaunchKernelGGL(gru_main, dim3(NBLK), dim3(256), 0, stream,
                     x, xmask, h0, Wih0, Whh0, bih0, bhh0,
                     Wih1, Whh1, bih1, bhh1, out, ws);
}